// Round 1
// baseline (1225.791 us; speedup 1.0000x reference)
//
#include <hip/hip_runtime.h>

typedef __attribute__((ext_vector_type(4))) float  f32x4;
typedef __attribute__((ext_vector_type(8))) short  short8;
typedef __attribute__((ext_vector_type(4))) short  short4v;
typedef __attribute__((ext_vector_type(8))) __bf16 bf16x8;

#define DEVI static __device__ __forceinline__

constexpr int Tc = 4096, Hc = 32, Cc = 64, HCc = Hc * Cc, Bc = 2;
constexpr int NTc = Tc / 16;     // 256 chunks
constexpr int SW = 72;           // row stride (shorts) for 16x64 bf16 arrays (144B, 16B-mult)
constexpr int ST = 24;           // row stride for 16x16 / 64x16 arrays (48B)
constexpr int SQ = 48;           // qk|qb merged stride (96B)

// float -> bf16 bits, round-to-nearest-even (inputs finite; no NaN handling needed)
DEVI short f2bs(float x){
  unsigned u = __builtin_bit_cast(unsigned, x);
  unsigned r = u + 0x7FFFu + ((u >> 16) & 1u);
  return (short)(r >> 16);
}
DEVI f32x4 MFMA(short8 a, short8 b, f32x4 c){
  return __builtin_amdgcn_mfma_f32_16x16x32_bf16(
      __builtin_bit_cast(bf16x8, a), __builtin_bit_cast(bf16x8, b), c, 0, 0, 0);
}
DEVI short8 ld8(const short* p){ return *(const short8*)p; }
DEVI short8 zero8(){ short8 z = {0,0,0,0,0,0,0,0}; return z; }
DEVI f32x4 zero4(){ f32x4 z = {0.f,0.f,0.f,0.f}; return z; }

struct Regs { float wv[16]; float xv[16]; float vv[8]; };

__global__ __launch_bounds__(256, 1)
void rwkv7_kernel(const float* __restrict__ w, const float* __restrict__ q,
                  const float* __restrict__ k, const float* __restrict__ v,
                  const float* __restrict__ a, const float* __restrict__ b,
                  float* __restrict__ out)
{
  // double-buffered chunk-local arrays (bf16 as shorts)
  __shared__ __align__(16) short s_wq[2][16*SW];
  __shared__ __align__(16) short s_wa[2][16*SW];
  __shared__ __align__(16) short s_kwi[2][16*SW];
  __shared__ __align__(16) short s_bwi[2][16*SW];
  __shared__ __align__(16) short s_kwT[2][64*ST];  // (kwi*fw) transposed [c][t]
  __shared__ __align__(16) short s_bwT[2][64*ST];  // (bwi*fw) transposed
  __shared__ __align__(16) short s_ak[2][16*ST];
  __shared__ __align__(16) short s_qq[2][16*SQ];   // [qk | qb] merged 16x32
  __shared__ __align__(16) short s_li[2][16*ST];   // Linv = (I-ab)^-1
  // wave0-local scratch for the nilpotent chain (single-buffered)
  __shared__ __align__(16) short s_n1[16*ST];
  __shared__ __align__(16) short s_n2[16*ST];
  __shared__ __align__(16) short s_n4[16*ST];
  // per-wave bf16 shadow of state slice (16ch x 64k)
  __shared__ __align__(16) short s_st[4][16*SW];

  const int tid = threadIdx.x;
  const int wid = tid >> 6;          // wave id = v-channel slice
  const int l   = tid & 63;
  const int q4  = l >> 4;
  const int m   = l & 15;

  const int bh = blockIdx.x;
  const size_t hb = (size_t)(bh >> 5) * Tc * HCc + (size_t)(bh & 31) * Cc;

  const float* xsrc = (wid == 0) ? q : (wid == 1) ? a : (wid == 2) ? k : b;
  const float* wB = w + hb + l;
  const float* xB = xsrc + hb + l;
  const float* vBp = v + hb + wid * 16 + m;
  float* yB = out + hb + wid * 16 + m;

  f32x4 sacc[4];
  #pragma unroll
  for (int i = 0; i < 4; i++) sacc[i] = zero4();
  for (int i = tid; i < 4 * 16 * SW; i += 256) (&s_st[0][0])[i] = 0;
  __syncthreads();

  auto loadc = [&](Regs& r, int n){
    const float* wp = wB + (size_t)n * 16 * HCc;
    const float* xp = xB + (size_t)n * 16 * HCc;
    const float* vp = vBp + (size_t)n * 16 * HCc;
    #pragma unroll
    for (int t = 0; t < 16; t++) r.wv[t] = wp[t * HCc];
    #pragma unroll
    for (int t = 0; t < 16; t++) r.xv[t] = xp[t * HCc];
    #pragma unroll
    for (int j = 0; j < 8; j++){
      int row = (q4 & 1) * 8 + j;            // valid rows for all lanes
      float val = vp[row * HCc];
      r.vv[j] = (q4 < 2) ? val : 0.f;
    }
  };

  // D-layout (row=(l>>4)*4+r, col=l&15) -> B-frag emulating K=16 on K=32 (upper zero)
  auto shufK16 = [&](f32x4 d) -> short8 {
    short8 r;
    #pragma unroll
    for (int j = 0; j < 8; j++){
      int row = q4 * 8 + j;
      int src = (((row >> 2) << 4) + m) & 63;
      float vv_ = __shfl(d[j & 3], src, 64);
      r[j] = (q4 < 2) ? f2bs(vv_) : (short)0;
    }
    return r;
  };

  auto body = [&](const Regs& rg, int n){
    const int bi = n & 1;
    // ---------- E: elementwise / decay ----------
    float run = 1.f;
    float kv[16];
    #pragma unroll
    for (int t = 0; t < 16; t++){
      float dec = __expf(-__expf(rg.wv[t]));
      float ni = run;            // non_incl = incl[t-1]
      run *= dec;                // incl[t]
      float x = rg.xv[t];
      if (wid == 0)      s_wq[bi][t * SW + l] = f2bs(x * run);
      else if (wid == 1) s_wa[bi][t * SW + l] = f2bs(x * ni);
      else {
        float kk = x * __builtin_amdgcn_rcpf(run);   // x * inv_incl
        kv[t] = kk;
        short* dst = (wid == 2) ? s_kwi[bi] : s_bwi[bi];
        dst[t * SW + l] = f2bs(kk);
      }
    }
    const float fwv = run;       // fw[c], c = l
    if (wid >= 2){
      short* dst = (wid == 2) ? s_kwT[bi] : s_bwT[bi];
      #pragma unroll
      for (int i = 0; i < 4; i++){
        short4v pk = { f2bs(kv[4*i]*fwv), f2bs(kv[4*i+1]*fwv),
                       f2bs(kv[4*i+2]*fwv), f2bs(kv[4*i+3]*fwv) };
        *(short4v*)&dst[l * ST + 4 * i] = pk;
      }
    }
    __syncthreads();
    // ---------- M: 16x16 matrices + Linv ----------
    {
      const short* Aarr = (wid < 2) ? s_wa[bi] : s_wq[bi];
      const short* Barr = (wid == 0 || wid == 3) ? s_bwi[bi] : s_kwi[bi];
      short8 A0 = ld8(&Aarr[m * SW + q4 * 8]);
      short8 A1 = ld8(&Aarr[m * SW + q4 * 8 + 32]);
      short8 B0 = ld8(&Barr[m * SW + q4 * 8]);
      short8 B1 = ld8(&Barr[m * SW + q4 * 8 + 32]);
      f32x4 mm = MFMA(A0, B0, zero4());
      mm = MFMA(A1, B1, mm);
      #pragma unroll
      for (int r = 0; r < 4; r++){
        int t = q4 * 4 + r;
        bool keep = (wid < 2) ? (m < t) : (m <= t);
        mm[r] = keep ? mm[r] : 0.f;
      }
      if (wid == 1){
        #pragma unroll
        for (int r = 0; r < 4; r++) s_ak[bi][(q4*4+r)*ST + m] = f2bs(mm[r]);
      } else if (wid == 2){
        #pragma unroll
        for (int r = 0; r < 4; r++) s_qq[bi][(q4*4+r)*SQ + m] = f2bs(mm[r]);
      } else if (wid == 3){
        #pragma unroll
        for (int r = 0; r < 4; r++) s_qq[bi][(q4*4+r)*SQ + 16 + m] = f2bs(mm[r]);
      } else {
        // wave0: Linv = (I+N)(I+N^2)(I+N^4)(I+N^8), N = ab (strictly lower)
        #pragma unroll
        for (int r = 0; r < 4; r++) s_n1[(q4*4+r)*ST + m] = f2bs(mm[r]);
        short8 a1 = (q4 < 2) ? ld8(&s_n1[m*ST + q4*8]) : zero8();
        f32x4 p2 = MFMA(a1, shufK16(mm), zero4());
        #pragma unroll
        for (int r = 0; r < 4; r++) s_n2[(q4*4+r)*ST + m] = f2bs(p2[r]);
        short8 a2 = (q4 < 2) ? ld8(&s_n2[m*ST + q4*8]) : zero8();
        f32x4 p4 = MFMA(a2, shufK16(p2), zero4());
        #pragma unroll
        for (int r = 0; r < 4; r++) s_n4[(q4*4+r)*ST + m] = f2bs(p4[r]);
        short8 a4 = (q4 < 2) ? ld8(&s_n4[m*ST + q4*8]) : zero8();
        f32x4 R = MFMA(a4, shufK16(p4), zero4());          // N^8
        #pragma unroll
        for (int r = 0; r < 4; r++) R[r] += ((q4*4+r) == m) ? 1.f : 0.f;  // I+N^8
        R = MFMA(a4, shufK16(R), R);                        // (I+N^4)R
        R = MFMA(a2, shufK16(R), R);                        // (I+N^2)R
        R = MFMA(a1, shufK16(R), R);                        // (I+N)R = Linv
        #pragma unroll
        for (int r = 0; r < 4; r++) s_li[bi][(q4*4+r)*ST + m] = f2bs(R[r]);
      }
    }
    __syncthreads();
    // ---------- D: state-dependent chain ----------
    {
      short8 vBf;
      #pragma unroll
      for (int j = 0; j < 8; j++) vBf[j] = (q4 < 2) ? f2bs(rg.vv[j]) : (short)0;
      short8 akA  = (q4 < 2) ? ld8(&s_ak[bi][m*ST + q4*8]) : zero8();
      short8 waA0 = ld8(&s_wa[bi][m*SW + q4*8]);
      short8 waA1 = ld8(&s_wa[bi][m*SW + q4*8 + 32]);
      short8 st0  = ld8(&s_st[wid][m*SW + q4*8]);
      short8 st1  = ld8(&s_st[wid][m*SW + q4*8 + 32]);
      f32x4 abu = MFMA(akA, vBf, zero4());     // ak @ v
      abu = MFMA(waA0, st0, abu);              // + wa @ state^T
      abu = MFMA(waA1, st1, abu);
      short8 LA = (q4 < 2) ? ld8(&s_li[bi][m*ST + q4*8]) : zero8();
      f32x4 uu = MFMA(LA, shufK16(abu), zero4());  // u = Linv @ ab_u
      // vu: lanes q4<2 carry v (k=0..15), q4>=2 carry u (k=16..31). Serves as
      // B-frag of [v;u] (y term) and A-frag of [v^T|u^T] (state term).
      short8 vu;
      #pragma unroll
      for (int j = 0; j < 8; j++){
        int row = (q4 - 2) * 8 + j;
        int src = (((row >> 2) << 4) + m) & 63;
        float uv = __shfl(uu[j & 3], src, 64);
        vu[j] = (q4 < 2) ? vBf[j] : f2bs(uv);
      }
      short8 qqA  = ld8(&s_qq[bi][m*SQ + q4*8]);   // [qk|qb] row m
      short8 wqA0 = ld8(&s_wq[bi][m*SW + q4*8]);
      short8 wqA1 = ld8(&s_wq[bi][m*SW + q4*8 + 32]);
      f32x4 yy = MFMA(qqA, vu, zero4());           // qk@v + qb@u
      yy = MFMA(wqA0, st0, yy);                    // + wq @ state^T
      yy = MFMA(wqA1, st1, yy);
      float* yp = yB + (size_t)(n * 16) * HCc;
      #pragma unroll
      for (int r = 0; r < 4; r++) yp[(q4*4 + r) * HCc] = yy[r];
      // state update: state = state*fw + [v^T|u^T] @ [kwi*fw ; bwi*fw]
      #pragma unroll
      for (int nt = 0; nt < 4; nt++){
        float fwk = __shfl(fwv, nt * 16 + m, 64);
        f32x4 s = sacc[nt];
        #pragma unroll
        for (int r = 0; r < 4; r++) s[r] *= fwk;
        const short* kb = (q4 < 2) ? &s_kwT[bi][(nt*16+m)*ST + q4*8]
                                   : &s_bwT[bi][(nt*16+m)*ST + (q4-2)*8];
        s = MFMA(vu, ld8(kb), s);
        sacc[nt] = s;
        #pragma unroll
        for (int r = 0; r < 4; r++)
          s_st[wid][(q4*4+r)*SW + nt*16 + m] = f2bs(s[r]);
      }
    }
  };

  Regs ra, rb;
  loadc(ra, 0);
  for (int n = 0; n < NTc; n += 2){
    loadc(rb, n + 1);
    body(ra, n);
    if (n + 2 < NTc) loadc(ra, n + 2);
    body(rb, n + 1);
  }
}

extern "C" void kernel_launch(void* const* d_in, const int* in_sizes, int n_in,
                              void* d_out, int out_size, void* d_ws, size_t ws_size,
                              hipStream_t stream)
{
  (void)in_sizes; (void)n_in; (void)d_ws; (void)ws_size; (void)out_size;
  const float* w = (const float*)d_in[0];
  const float* q = (const float*)d_in[1];
  const float* k = (const float*)d_in[2];
  const float* v = (const float*)d_in[3];
  const float* a = (const float*)d_in[4];
  const float* b = (const float*)d_in[5];
  float* out = (float*)d_out;
  rwkv7_kernel<<<dim3(Bc * Hc), dim3(256), 0, stream>>>(w, q, k, v, a, b, out);
}

// Round 2
// 609.194 us; speedup vs baseline: 2.0122x; 2.0122x over previous
//
#include <hip/hip_runtime.h>

typedef __attribute__((ext_vector_type(4))) float  f32x4;
typedef __attribute__((ext_vector_type(8))) short  short8;
typedef __attribute__((ext_vector_type(4))) short  short4v;
typedef __attribute__((ext_vector_type(8))) __bf16 bf16x8;

#define DEVI static __device__ __forceinline__

constexpr int Tc = 4096, Hc = 32, Cc = 64, HCc = Hc * Cc, Bc = 2;
constexpr int NTc = Tc / 16;     // 256 chunks
constexpr int SW = 72;           // row stride (shorts) for 16x64 bf16 arrays (144B)
constexpr int ST = 24;           // row stride for 16x16 arrays (48B)
constexpr int SQc = 48;          // fallback kernel qq stride

// ---- blob layout (shorts) ----
constexpr int SKT = 40;          // kbT row stride (80B, 16B-mult)
constexpr int SAK = 24;
constexpr int SQQ = 56;
constexpr int SLI = 24;
constexpr int WAo = 0;            // wa: 16 x SW
constexpr int WQo = WAo + 16*SW;  // wq: 16 x SW        = 1152
constexpr int KBo = WQo + 16*SW;  // kbT: 64 x SKT      = 2304
constexpr int AKo = KBo + 64*SKT; // ak: 16 x SAK       = 4864
constexpr int QQo = AKo + 16*SAK; // [qk|qb]: 16 x SQQ  = 5248
constexpr int LIo = QQo + 16*SQQ; // Linv: 16 x SLI     = 6144
constexpr int FWo = LIo + 16*SLI; // fw: 64 floats      = 6528
constexpr int CS  = FWo + 128;    // 6656 shorts = 13312 B per chunk

DEVI short f2bs(float x){
  unsigned u = __builtin_bit_cast(unsigned, x);
  unsigned r = u + 0x7FFFu + ((u >> 16) & 1u);
  return (short)(r >> 16);
}
DEVI f32x4 MFMA(short8 a, short8 b, f32x4 c){
  return __builtin_amdgcn_mfma_f32_16x16x32_bf16(
      __builtin_bit_cast(bf16x8, a), __builtin_bit_cast(bf16x8, b), c, 0, 0, 0);
}
DEVI short8 ld8(const short* p){ return *(const short8*)p; }
DEVI short8 zero8(){ short8 z = {0,0,0,0,0,0,0,0}; return z; }
DEVI f32x4 zero4(){ f32x4 z = {0.f,0.f,0.f,0.f}; return z; }

// D-frag (row=(l>>4)*4+r, col=l&15) -> B-frag emulating K=16 on K=32 (upper zero)
DEVI short8 shufK16(f32x4 d, int q4, int m){
  short8 r;
  #pragma unroll
  for (int j = 0; j < 8; j++){
    int row = q4 * 8 + j;
    int src = (((row >> 2) << 4) + m) & 63;
    float vv_ = __shfl(d[j & 3], src, 64);
    r[j] = (q4 < 2) ? f2bs(vv_) : (short)0;
  }
  return r;
}

// ================= k1: parallel per-chunk prep =================
__global__ __launch_bounds__(256, 1)
void rwkv7_prep(const float* __restrict__ w, const float* __restrict__ q,
                const float* __restrict__ k, const float* __restrict__ a,
                const float* __restrict__ b, short* __restrict__ blob)
{
  __shared__ __align__(16) short img[CS];
  __shared__ __align__(16) short s_kwi[16*SW];
  __shared__ __align__(16) short s_bwi[16*SW];
  __shared__ __align__(16) short s_n1[16*SLI];
  __shared__ __align__(16) short s_n2[16*SLI];
  __shared__ __align__(16) short s_n4[16*SLI];

  const int tid = threadIdx.x, wid = tid >> 6, l = tid & 63;
  const int q4 = l >> 4, m = l & 15;
  const int bid = blockIdx.x, bh = bid >> 8, n = bid & 255;
  const size_t hb = (size_t)(bh >> 5) * Tc * HCc + (size_t)(bh & 31) * Cc
                  + (size_t)n * 16 * HCc;
  const float* xsrc = (wid == 0) ? q : (wid == 1) ? a : (wid == 2) ? k : b;
  const float* wp = w + hb + l;
  const float* xp = xsrc + hb + l;

  float wv[16], xv[16];
  #pragma unroll
  for (int t = 0; t < 16; t++) wv[t] = wp[t * HCc];
  #pragma unroll
  for (int t = 0; t < 16; t++) xv[t] = xp[t * HCc];

  // ---- E: decay / elementwise ----
  float run = 1.f, kv[16];
  #pragma unroll
  for (int t = 0; t < 16; t++){
    float dec = __expf(-__expf(wv[t]));
    float ni = run;
    run *= dec;
    float x = xv[t];
    if (wid == 0)      img[WQo + t*SW + l] = f2bs(x * run);
    else if (wid == 1) img[WAo + t*SW + l] = f2bs(x * ni);
    else {
      float kk = x * __builtin_amdgcn_rcpf(run);
      kv[t] = kk;
      (wid == 2 ? s_kwi : s_bwi)[t*SW + l] = f2bs(kk);
    }
  }
  if (wid == 0) ((float*)&img[FWo])[l] = run;   // fw[c], c = l
  if (wid >= 2){
    const int co = (wid == 2) ? 0 : 16;
    #pragma unroll
    for (int i = 0; i < 4; i++){
      short4v pk = { f2bs(kv[4*i]*run),   f2bs(kv[4*i+1]*run),
                     f2bs(kv[4*i+2]*run), f2bs(kv[4*i+3]*run) };
      *(short4v*)&img[KBo + l*SKT + co + 4*i] = pk;
    }
  }
  __syncthreads();

  // ---- M: 16x16 matrices + Linv ----
  {
    const short* Aarr = (wid < 2) ? &img[WAo] : &img[WQo];
    const short* Barr = (wid == 0 || wid == 3) ? s_bwi : s_kwi;
    short8 A0 = ld8(&Aarr[m*SW + q4*8]);
    short8 A1 = ld8(&Aarr[m*SW + q4*8 + 32]);
    short8 B0 = ld8(&Barr[m*SW + q4*8]);
    short8 B1 = ld8(&Barr[m*SW + q4*8 + 32]);
    f32x4 mm = MFMA(A0, B0, zero4());
    mm = MFMA(A1, B1, mm);
    #pragma unroll
    for (int r = 0; r < 4; r++){
      int t = q4*4 + r;
      bool keep = (wid < 2) ? (m < t) : (m <= t);
      mm[r] = keep ? mm[r] : 0.f;
    }
    if (wid == 1){
      #pragma unroll
      for (int r = 0; r < 4; r++) img[AKo + (q4*4+r)*SAK + m] = f2bs(mm[r]);
    } else if (wid == 2){
      #pragma unroll
      for (int r = 0; r < 4; r++) img[QQo + (q4*4+r)*SQQ + m] = f2bs(mm[r]);
    } else if (wid == 3){
      #pragma unroll
      for (int r = 0; r < 4; r++) img[QQo + (q4*4+r)*SQQ + 16 + m] = f2bs(mm[r]);
    } else {
      // Linv = (I+N)(I+N^2)(I+N^4)(I+N^8), N = ab strictly lower
      #pragma unroll
      for (int r = 0; r < 4; r++) s_n1[(q4*4+r)*SLI + m] = f2bs(mm[r]);
      short8 a1 = (q4 < 2) ? ld8(&s_n1[m*SLI + q4*8]) : zero8();
      f32x4 p2 = MFMA(a1, shufK16(mm, q4, m), zero4());
      #pragma unroll
      for (int r = 0; r < 4; r++) s_n2[(q4*4+r)*SLI + m] = f2bs(p2[r]);
      short8 a2 = (q4 < 2) ? ld8(&s_n2[m*SLI + q4*8]) : zero8();
      f32x4 p4 = MFMA(a2, shufK16(p2, q4, m), zero4());
      #pragma unroll
      for (int r = 0; r < 4; r++) s_n4[(q4*4+r)*SLI + m] = f2bs(p4[r]);
      short8 a4 = (q4 < 2) ? ld8(&s_n4[m*SLI + q4*8]) : zero8();
      f32x4 R = MFMA(a4, shufK16(p4, q4, m), zero4());          // N^8
      #pragma unroll
      for (int r = 0; r < 4; r++) R[r] += ((q4*4+r) == m) ? 1.f : 0.f;
      R = MFMA(a4, shufK16(R, q4, m), R);
      R = MFMA(a2, shufK16(R, q4, m), R);
      R = MFMA(a1, shufK16(R, q4, m), R);
      #pragma unroll
      for (int r = 0; r < 4; r++) img[LIo + (q4*4+r)*SLI + m] = f2bs(R[r]);
    }
  }
  __syncthreads();

  // ---- copy blob image to global ----
  short* dst = blob + (size_t)bid * CS;
  #pragma unroll
  for (int it = 0; it < 4; it++){
    int i = tid*8 + it*2048;
    if (i < CS) *(short8*)(dst + i) = *(const short8*)(&img[i]);
  }
}

// ================= k2: sequential scan =================
__global__ __launch_bounds__(256, 1)
void rwkv7_scan(const short* __restrict__ blob, const float* __restrict__ v,
                float* __restrict__ out)
{
  __shared__ __align__(16) short buf[2][CS];
  __shared__ __align__(16) short s_st[4][16*SW];

  const int tid = threadIdx.x, wid = tid >> 6, l = tid & 63;
  const int q4 = l >> 4, m = l & 15;
  const int bh = blockIdx.x;
  const size_t hb = (size_t)(bh >> 5) * Tc * HCc + (size_t)(bh & 31) * Cc;
  const float* vBp = v + hb + wid*16 + m;
  float* yB = out + hb + wid*16 + m;
  const short* bB = blob + (size_t)bh * NTc * CS;

  f32x4 sacc[4];
  #pragma unroll
  for (int i = 0; i < 4; i++) sacc[i] = zero4();
  for (int i = tid; i < 4*16*SW; i += 256) (&s_st[0][0])[i] = 0;

  struct VR { float vv[8]; };
  auto loadv = [&](VR& r, int nn){
    const float* vp = vBp + (size_t)nn * 16 * HCc;
    #pragma unroll
    for (int j = 0; j < 8; j++){
      int row = (q4 & 1) * 8 + j;
      float val = vp[row * HCc];
      r.vv[j] = (q4 < 2) ? val : 0.f;
    }
  };
  auto issueLoads = [&](short8* st, int nn){
    const short* src = bB + (size_t)nn * CS;
    #pragma unroll
    for (int it = 0; it < 4; it++){
      int i = tid*8 + it*2048;
      st[it] = (i < CS) ? *(const short8*)(src + i) : zero8();
    }
  };
  auto writeStage = [&](const short8* st, int nn){
    short* lb = &buf[nn & 1][0];
    #pragma unroll
    for (int it = 0; it < 4; it++){
      int i = tid*8 + it*2048;
      if (i < CS) *(short8*)(lb + i) = st[it];
    }
  };

  auto body = [&](const VR& rg, int n){
    const short* bp = &buf[n & 1][0];
    short8 vBf;
    #pragma unroll
    for (int j = 0; j < 8; j++) vBf[j] = (q4 < 2) ? f2bs(rg.vv[j]) : (short)0;
    short8 akA  = (q4 < 2) ? ld8(&bp[AKo + m*SAK + q4*8]) : zero8();
    short8 waA0 = ld8(&bp[WAo + m*SW + q4*8]);
    short8 waA1 = ld8(&bp[WAo + m*SW + q4*8 + 32]);
    short8 st0  = ld8(&s_st[wid][m*SW + q4*8]);
    short8 st1  = ld8(&s_st[wid][m*SW + q4*8 + 32]);
    f32x4 abu = MFMA(akA, vBf, zero4());     // ak @ v
    abu = MFMA(waA0, st0, abu);              // + wa @ state^T
    abu = MFMA(waA1, st1, abu);
    short8 LA = (q4 < 2) ? ld8(&bp[LIo + m*SLI + q4*8]) : zero8();
    f32x4 uu = MFMA(LA, shufK16(abu, q4, m), zero4());   // u = Linv @ ab_u
    short8 vu;
    #pragma unroll
    for (int j = 0; j < 8; j++){
      int row = (q4 - 2) * 8 + j;
      int src = (((row >> 2) << 4) + m) & 63;
      float uv = __shfl(uu[j & 3], src, 64);
      vu[j] = (q4 < 2) ? vBf[j] : f2bs(uv);
    }
    short8 qqA  = ld8(&bp[QQo + m*SQQ + q4*8]);
    short8 wqA0 = ld8(&bp[WQo + m*SW + q4*8]);
    short8 wqA1 = ld8(&bp[WQo + m*SW + q4*8 + 32]);
    f32x4 yy = MFMA(qqA, vu, zero4());       // qk@v + qb@u
    yy = MFMA(wqA0, st0, yy);
    yy = MFMA(wqA1, st1, yy);
    float* yp = yB + (size_t)(n * 16) * HCc;
    #pragma unroll
    for (int r = 0; r < 4; r++) yp[(q4*4 + r) * HCc] = yy[r];
    const float* fwp = (const float*)&bp[FWo];
    #pragma unroll
    for (int nt = 0; nt < 4; nt++){
      float fwk = fwp[nt*16 + m];
      f32x4 s = sacc[nt];
      #pragma unroll
      for (int r = 0; r < 4; r++) s[r] *= fwk;
      s = MFMA(vu, ld8(&bp[KBo + (nt*16+m)*SKT + q4*8]), s);
      sacc[nt] = s;
      #pragma unroll
      for (int r = 0; r < 4; r++)
        s_st[wid][(q4*4+r)*SW + nt*16 + m] = f2bs(s[r]);
    }
  };

  VR ra, rb;
  short8 sA[4], sB[4];
  issueLoads(sA, 0); writeStage(sA, 0);      // buf0 <- chunk 0
  issueLoads(sB, 1);                          // chunk 1 into regs
  loadv(ra, 0);
  for (int n = 0; n < NTc; n += 2){
    __syncthreads();                          // buf[n&1] ready (all waves)
    writeStage(sB, n + 1);                    // buf1 <- chunk n+1
    loadv(rb, n + 1);
    body(ra, n);                              // reads buf0
    if (n + 2 < NTc) issueLoads(sA, n + 2);
    __syncthreads();                          // buf1 ready
    if (n + 2 < NTc){ writeStage(sA, n + 2); loadv(ra, n + 2); }
    body(rb, n + 1);                          // reads buf1
    if (n + 3 < NTc) issueLoads(sB, n + 3);
  }
}

// ================= fallback: single fused kernel (round-1, passing) ==========
struct Regs { float wv[16]; float xv[16]; float vv[8]; };

__global__ __launch_bounds__(256, 1)
void rwkv7_kernel(const float* __restrict__ w, const float* __restrict__ q,
                  const float* __restrict__ k, const float* __restrict__ v,
                  const float* __restrict__ a, const float* __restrict__ b,
                  float* __restrict__ out)
{
  __shared__ __align__(16) short s_wq[2][16*SW];
  __shared__ __align__(16) short s_wa[2][16*SW];
  __shared__ __align__(16) short s_kwi[2][16*SW];
  __shared__ __align__(16) short s_bwi[2][16*SW];
  __shared__ __align__(16) short s_kwT[2][64*ST];
  __shared__ __align__(16) short s_bwT[2][64*ST];
  __shared__ __align__(16) short s_ak[2][16*ST];
  __shared__ __align__(16) short s_qq[2][16*SQc];
  __shared__ __align__(16) short s_li[2][16*ST];
  __shared__ __align__(16) short s_n1[16*ST];
  __shared__ __align__(16) short s_n2[16*ST];
  __shared__ __align__(16) short s_n4[16*ST];
  __shared__ __align__(16) short s_st[4][16*SW];

  const int tid = threadIdx.x;
  const int wid = tid >> 6;
  const int l   = tid & 63;
  const int q4  = l >> 4;
  const int m   = l & 15;

  const int bh = blockIdx.x;
  const size_t hb = (size_t)(bh >> 5) * Tc * HCc + (size_t)(bh & 31) * Cc;

  const float* xsrc = (wid == 0) ? q : (wid == 1) ? a : (wid == 2) ? k : b;
  const float* wB = w + hb + l;
  const float* xB = xsrc + hb + l;
  const float* vBp = v + hb + wid * 16 + m;
  float* yB = out + hb + wid * 16 + m;

  f32x4 sacc[4];
  #pragma unroll
  for (int i = 0; i < 4; i++) sacc[i] = zero4();
  for (int i = tid; i < 4 * 16 * SW; i += 256) (&s_st[0][0])[i] = 0;
  __syncthreads();

  auto loadc = [&](Regs& r, int n){
    const float* wp = wB + (size_t)n * 16 * HCc;
    const float* xp = xB + (size_t)n * 16 * HCc;
    const float* vp = vBp + (size_t)n * 16 * HCc;
    #pragma unroll
    for (int t = 0; t < 16; t++) r.wv[t] = wp[t * HCc];
    #pragma unroll
    for (int t = 0; t < 16; t++) r.xv[t] = xp[t * HCc];
    #pragma unroll
    for (int j = 0; j < 8; j++){
      int row = (q4 & 1) * 8 + j;
      float val = vp[row * HCc];
      r.vv[j] = (q4 < 2) ? val : 0.f;
    }
  };

  auto body = [&](const Regs& rg, int n){
    const int bi = n & 1;
    float run = 1.f;
    float kv[16];
    #pragma unroll
    for (int t = 0; t < 16; t++){
      float dec = __expf(-__expf(rg.wv[t]));
      float ni = run;
      run *= dec;
      float x = rg.xv[t];
      if (wid == 0)      s_wq[bi][t * SW + l] = f2bs(x * run);
      else if (wid == 1) s_wa[bi][t * SW + l] = f2bs(x * ni);
      else {
        float kk = x * __builtin_amdgcn_rcpf(run);
        kv[t] = kk;
        short* dst = (wid == 2) ? s_kwi[bi] : s_bwi[bi];
        dst[t * SW + l] = f2bs(kk);
      }
    }
    const float fwv = run;
    if (wid >= 2){
      short* dst = (wid == 2) ? s_kwT[bi] : s_bwT[bi];
      #pragma unroll
      for (int i = 0; i < 4; i++){
        short4v pk = { f2bs(kv[4*i]*fwv), f2bs(kv[4*i+1]*fwv),
                       f2bs(kv[4*i+2]*fwv), f2bs(kv[4*i+3]*fwv) };
        *(short4v*)&dst[l * ST + 4 * i] = pk;
      }
    }
    __syncthreads();
    {
      const short* Aarr = (wid < 2) ? s_wa[bi] : s_wq[bi];
      const short* Barr = (wid == 0 || wid == 3) ? s_bwi[bi] : s_kwi[bi];
      short8 A0 = ld8(&Aarr[m * SW + q4 * 8]);
      short8 A1 = ld8(&Aarr[m * SW + q4 * 8 + 32]);
      short8 B0 = ld8(&Barr[m * SW + q4 * 8]);
      short8 B1 = ld8(&Barr[m * SW + q4 * 8 + 32]);
      f32x4 mm = MFMA(A0, B0, zero4());
      mm = MFMA(A1, B1, mm);
      #pragma unroll
      for (int r = 0; r < 4; r++){
        int t = q4 * 4 + r;
        bool keep = (wid < 2) ? (m < t) : (m <= t);
        mm[r] = keep ? mm[r] : 0.f;
      }
      if (wid == 1){
        #pragma unroll
        for (int r = 0; r < 4; r++) s_ak[bi][(q4*4+r)*ST + m] = f2bs(mm[r]);
      } else if (wid == 2){
        #pragma unroll
        for (int r = 0; r < 4; r++) s_qq[bi][(q4*4+r)*SQc + m] = f2bs(mm[r]);
      } else if (wid == 3){
        #pragma unroll
        for (int r = 0; r < 4; r++) s_qq[bi][(q4*4+r)*SQc + 16 + m] = f2bs(mm[r]);
      } else {
        #pragma unroll
        for (int r = 0; r < 4; r++) s_n1[(q4*4+r)*ST + m] = f2bs(mm[r]);
        short8 a1 = (q4 < 2) ? ld8(&s_n1[m*ST + q4*8]) : zero8();
        f32x4 p2 = MFMA(a1, shufK16(mm, q4, m), zero4());
        #pragma unroll
        for (int r = 0; r < 4; r++) s_n2[(q4*4+r)*ST + m] = f2bs(p2[r]);
        short8 a2 = (q4 < 2) ? ld8(&s_n2[m*ST + q4*8]) : zero8();
        f32x4 p4 = MFMA(a2, shufK16(p2, q4, m), zero4());
        #pragma unroll
        for (int r = 0; r < 4; r++) s_n4[(q4*4+r)*ST + m] = f2bs(p4[r]);
        short8 a4 = (q4 < 2) ? ld8(&s_n4[m*ST + q4*8]) : zero8();
        f32x4 R = MFMA(a4, shufK16(p4, q4, m), zero4());
        #pragma unroll
        for (int r = 0; r < 4; r++) R[r] += ((q4*4+r) == m) ? 1.f : 0.f;
        R = MFMA(a4, shufK16(R, q4, m), R);
        R = MFMA(a2, shufK16(R, q4, m), R);
        R = MFMA(a1, shufK16(R, q4, m), R);
        #pragma unroll
        for (int r = 0; r < 4; r++) s_li[bi][(q4*4+r)*ST + m] = f2bs(R[r]);
      }
    }
    __syncthreads();
    {
      short8 vBf;
      #pragma unroll
      for (int j = 0; j < 8; j++) vBf[j] = (q4 < 2) ? f2bs(rg.vv[j]) : (short)0;
      short8 akA  = (q4 < 2) ? ld8(&s_ak[bi][m*ST + q4*8]) : zero8();
      short8 waA0 = ld8(&s_wa[bi][m*SW + q4*8]);
      short8 waA1 = ld8(&s_wa[bi][m*SW + q4*8 + 32]);
      short8 st0  = ld8(&s_st[wid][m*SW + q4*8]);
      short8 st1  = ld8(&s_st[wid][m*SW + q4*8 + 32]);
      f32x4 abu = MFMA(akA, vBf, zero4());
      abu = MFMA(waA0, st0, abu);
      abu = MFMA(waA1, st1, abu);
      short8 LA = (q4 < 2) ? ld8(&s_li[bi][m*ST + q4*8]) : zero8();
      f32x4 uu = MFMA(LA, shufK16(abu, q4, m), zero4());
      short8 vu;
      #pragma unroll
      for (int j = 0; j < 8; j++){
        int row = (q4 - 2) * 8 + j;
        int src = (((row >> 2) << 4) + m) & 63;
        float uv = __shfl(uu[j & 3], src, 64);
        vu[j] = (q4 < 2) ? vBf[j] : f2bs(uv);
      }
      short8 qqA  = ld8(&s_qq[bi][m*SQc + q4*8]);
      short8 wqA0 = ld8(&s_wq[bi][m*SW + q4*8]);
      short8 wqA1 = ld8(&s_wq[bi][m*SW + q4*8 + 32]);
      f32x4 yy = MFMA(qqA, vu, zero4());
      yy = MFMA(wqA0, st0, yy);
      yy = MFMA(wqA1, st1, yy);
      float* yp = yB + (size_t)(n * 16) * HCc;
      #pragma unroll
      for (int r = 0; r < 4; r++) yp[(q4*4 + r) * HCc] = yy[r];
      #pragma unroll
      for (int nt = 0; nt < 4; nt++){
        float fwk = __shfl(fwv, nt * 16 + m, 64);
        f32x4 s = sacc[nt];
        #pragma unroll
        for (int r = 0; r < 4; r++) s[r] *= fwk;
        const short* kb = (q4 < 2) ? &s_kwT[bi][(nt*16+m)*ST + q4*8]
                                   : &s_bwT[bi][(nt*16+m)*ST + (q4-2)*8];
        s = MFMA(vu, ld8(kb), s);
        sacc[nt] = s;
        #pragma unroll
        for (int r = 0; r < 4; r++)
          s_st[wid][(q4*4+r)*SW + nt*16 + m] = f2bs(s[r]);
      }
    }
  };

  Regs ra, rb;
  loadc(ra, 0);
  for (int n = 0; n < NTc; n += 2){
    loadc(rb, n + 1);
    body(ra, n);
    if (n + 2 < NTc) loadc(ra, n + 2);
    body(rb, n + 1);
  }
}

extern "C" void kernel_launch(void* const* d_in, const int* in_sizes, int n_in,
                              void* d_out, int out_size, void* d_ws, size_t ws_size,
                              hipStream_t stream)
{
  (void)in_sizes; (void)n_in; (void)out_size;
  const float* w = (const float*)d_in[0];
  const float* q = (const float*)d_in[1];
  const float* k = (const float*)d_in[2];
  const float* v = (const float*)d_in[3];
  const float* a = (const float*)d_in[4];
  const float* b = (const float*)d_in[5];
  float* out = (float*)d_out;

  const size_t need = (size_t)Bc * Hc * NTc * CS * sizeof(short); // ~218 MB
  if (ws_size >= need){
    rwkv7_prep<<<dim3(Bc * Hc * NTc), dim3(256), 0, stream>>>(w, q, k, a, b, (short*)d_ws);
    rwkv7_scan<<<dim3(Bc * Hc), dim3(256), 0, stream>>>((const short*)d_ws, v, out);
  } else {
    rwkv7_kernel<<<dim3(Bc * Hc), dim3(256), 0, stream>>>(w, q, k, v, a, b, out);
  }
}

// Round 4
// 482.216 us; speedup vs baseline: 2.5420x; 1.2633x over previous
//
#include <hip/hip_runtime.h>

typedef __attribute__((ext_vector_type(4))) float  f32x4;
typedef __attribute__((ext_vector_type(8))) short  short8;
typedef __attribute__((ext_vector_type(4))) short  short4v;
typedef __attribute__((ext_vector_type(8))) __bf16 bf16x8;

#define DEVI static __device__ __forceinline__

constexpr int Tc = 4096, Hc = 32, Cc = 64, HCc = Hc * Cc, Bc = 2;
constexpr int NTc = Tc / 16;     // 256 chunks

// ---- packed, fragment-ready blob layout (shorts per chunk) ----
constexpr int WAb = 0;            // wa: 16x64 packed row-major
constexpr int WQb = 1024;         // wq: 16x64
constexpr int KBb = 2048;         // kb A-frag: nt(4) x lane(64) x 8
constexpr int AKb = 4096;         // ak: 16x16
constexpr int QQb = 4352;         // [qk|qb]: 16x32
constexpr int LIb = 4864;         // Linv: 16x16
constexpr int FWb = 5120;         // fw: 64 f32 = 128 shorts
constexpr int CS2 = 5248;         // 10496 B per chunk (16B-aligned)

// padded LDS strides (prep + state shadow)
constexpr int SW = 72;            // 144B rows, conflict-safe
constexpr int SLI = 24;
// fallback kernel strides
constexpr int ST = 24;
constexpr int SQc = 48;

DEVI short f2bs(float x){
  unsigned u = __builtin_bit_cast(unsigned, x);
  unsigned r = u + 0x7FFFu + ((u >> 16) & 1u);
  return (short)(r >> 16);
}
DEVI f32x4 MFMA(short8 a, short8 b, f32x4 c){
  return __builtin_amdgcn_mfma_f32_16x16x32_bf16(
      __builtin_bit_cast(bf16x8, a), __builtin_bit_cast(bf16x8, b), c, 0, 0, 0);
}
DEVI short8 ld8(const short* p){ return *(const short8*)p; }
DEVI short8 zero8(){ short8 z = {0,0,0,0,0,0,0,0}; return z; }
DEVI f32x4 zero4(){ f32x4 z = {0.f,0.f,0.f,0.f}; return z; }

// D-frag (row=(l>>4)*4+r, col=l&15) -> B-frag emulating K=16 on K=32 (upper zero)
DEVI short8 shufK16(f32x4 d, int q4, int m){
  short8 r;
  #pragma unroll
  for (int j = 0; j < 8; j++){
    int row = q4 * 8 + j;
    int src = (((row >> 2) << 4) + m) & 63;
    float vv_ = __shfl(d[j & 3], src, 64);
    r[j] = (q4 < 2) ? f2bs(vv_) : (short)0;
  }
  return r;
}

// ================= k1: parallel per-chunk prep =================
__global__ __launch_bounds__(256, 2)
void rwkv7_prep(const float* __restrict__ w, const float* __restrict__ q,
                const float* __restrict__ k, const float* __restrict__ a,
                const float* __restrict__ b, short* __restrict__ blob)
{
  __shared__ __align__(16) short img[CS2];
  __shared__ __align__(16) short s_wa[16*SW];
  __shared__ __align__(16) short s_wq[16*SW];
  __shared__ __align__(16) short s_kwi[16*SW];
  __shared__ __align__(16) short s_bwi[16*SW];
  __shared__ __align__(16) short s_n1[16*SLI];
  __shared__ __align__(16) short s_n2[16*SLI];
  __shared__ __align__(16) short s_n4[16*SLI];

  const int tid = threadIdx.x, wid = tid >> 6, l = tid & 63;
  const int q4 = l >> 4, m = l & 15;
  const int bid = blockIdx.x, bh = bid >> 8, n = bid & 255;
  const size_t hb = (size_t)(bh >> 5) * Tc * HCc + (size_t)(bh & 31) * Cc
                  + (size_t)n * 16 * HCc;
  const float* xsrc = (wid == 0) ? q : (wid == 1) ? a : (wid == 2) ? k : b;
  const float* wp = w + hb + l;
  const float* xp = xsrc + hb + l;

  float wv[16], xv[16];
  #pragma unroll
  for (int t = 0; t < 16; t++) wv[t] = wp[t * HCc];
  #pragma unroll
  for (int t = 0; t < 16; t++) xv[t] = xp[t * HCc];

  // ---- E: decay / elementwise ----
  float run = 1.f, kv[16];
  #pragma unroll
  for (int t = 0; t < 16; t++){
    float dec = __expf(-__expf(wv[t]));
    float ni = run;
    run *= dec;
    float x = xv[t];
    if (wid == 0){
      short s = f2bs(x * run);            // wq = q * incl
      s_wq[t*SW + l] = s;
      img[WQb + t*64 + l] = s;
    } else if (wid == 1){
      short s = f2bs(x * ni);             // wa = a * non_incl
      s_wa[t*SW + l] = s;
      img[WAb + t*64 + l] = s;
    } else {
      float kk = x * __builtin_amdgcn_rcpf(run);
      kv[t] = kk;
      (wid == 2 ? s_kwi : s_bwi)[t*SW + l] = f2bs(kk);
    }
  }
  if (wid == 0) ((float*)&img[FWb])[l] = run;   // fw[c], c = l
  if (wid >= 2){
    // kb A-frag region: lane (q4s,mm) of scan reads kwfw/bwfw[t=q4s*8+j][nt*16+mm]
    short8 p0, p1;
    #pragma unroll
    for (int j = 0; j < 8; j++){ p0[j] = f2bs(kv[j]*run); p1[j] = f2bs(kv[8+j]*run); }
    int base = KBb + (l >> 4)*512 + (l & 15)*8 + ((wid == 3) ? 256 : 0);
    *(short8*)&img[base]       = p0;
    *(short8*)&img[base + 128] = p1;
  }
  __syncthreads();

  // ---- M: 16x16 matrices + Linv ----
  {
    const short* Aarr = (wid < 2) ? s_wa : s_wq;
    const short* Barr = (wid == 0 || wid == 3) ? s_bwi : s_kwi;
    short8 A0 = ld8(&Aarr[m*SW + q4*8]);
    short8 A1 = ld8(&Aarr[m*SW + q4*8 + 32]);
    short8 B0 = ld8(&Barr[m*SW + q4*8]);
    short8 B1 = ld8(&Barr[m*SW + q4*8 + 32]);
    f32x4 mm = MFMA(A0, B0, zero4());
    mm = MFMA(A1, B1, mm);
    #pragma unroll
    for (int r = 0; r < 4; r++){
      int t = q4*4 + r;
      bool keep = (wid < 2) ? (m < t) : (m <= t);
      mm[r] = keep ? mm[r] : 0.f;
    }
    if (wid == 1){
      #pragma unroll
      for (int r = 0; r < 4; r++) img[AKb + (q4*4+r)*16 + m] = f2bs(mm[r]);
    } else if (wid == 2){
      #pragma unroll
      for (int r = 0; r < 4; r++) img[QQb + (q4*4+r)*32 + m] = f2bs(mm[r]);
    } else if (wid == 3){
      #pragma unroll
      for (int r = 0; r < 4; r++) img[QQb + (q4*4+r)*32 + 16 + m] = f2bs(mm[r]);
    } else {
      // Linv = (I+N)(I+N^2)(I+N^4)(I+N^8), N = ab strictly lower
      #pragma unroll
      for (int r = 0; r < 4; r++) s_n1[(q4*4+r)*SLI + m] = f2bs(mm[r]);
      short8 a1 = (q4 < 2) ? ld8(&s_n1[m*SLI + q4*8]) : zero8();
      f32x4 p2 = MFMA(a1, shufK16(mm, q4, m), zero4());
      #pragma unroll
      for (int r = 0; r < 4; r++) s_n2[(q4*4+r)*SLI + m] = f2bs(p2[r]);
      short8 a2 = (q4 < 2) ? ld8(&s_n2[m*SLI + q4*8]) : zero8();
      f32x4 p4 = MFMA(a2, shufK16(p2, q4, m), zero4());
      #pragma unroll
      for (int r = 0; r < 4; r++) s_n4[(q4*4+r)*SLI + m] = f2bs(p4[r]);
      short8 a4 = (q4 < 2) ? ld8(&s_n4[m*SLI + q4*8]) : zero8();
      f32x4 R = MFMA(a4, shufK16(p4, q4, m), zero4());          // N^8
      #pragma unroll
      for (int r = 0; r < 4; r++) R[r] += ((q4*4+r) == m) ? 1.f : 0.f;
      R = MFMA(a4, shufK16(R, q4, m), R);
      R = MFMA(a2, shufK16(R, q4, m), R);
      R = MFMA(a1, shufK16(R, q4, m), R);
      #pragma unroll
      for (int r = 0; r < 4; r++) img[LIb + (q4*4+r)*16 + m] = f2bs(R[r]);
    }
  }
  __syncthreads();

  // ---- copy blob image to global ----
  short* dst = blob + (size_t)bid * CS2;
  #pragma unroll
  for (int it = 0; it < 3; it++){
    int i = tid*8 + it*2048;
    if (i < CS2) *(short8*)(dst + i) = *(const short8*)(&img[i]);
  }
}

// ================= k2: sequential scan (barrier-free) =================
struct Frag {
  short8 wa0, wa1, wq0, wq1, qq, ak, li;
  short8 kb0, kb1, kb2, kb3;
  f32x4 fw0, fw1, fw2, fw3;
  float vv[8];
};

__global__ __launch_bounds__(256, 1)
void rwkv7_scan(const short* __restrict__ blob, const float* __restrict__ v,
                float* __restrict__ out)
{
  // per-wave state shadow S[v][k] (bf16), private per wave -> no barriers
  __shared__ __align__(16) short s_st[4][16*SW];

  const int tid = threadIdx.x, wid = tid >> 6, l = tid & 63;
  const int q4 = l >> 4, m = l & 15;
  const int bh = blockIdx.x;
  const size_t hb = (size_t)(bh >> 5) * Tc * HCc + (size_t)(bh & 31) * Cc;
  const float* vBp = v + hb + wid*16 + m;
  float* yB = out + hb + wid*16 + m;
  const short* bB = blob + (size_t)bh * NTc * CS2;

  for (int i = l; i < 16*SW; i += 64) s_st[wid][i] = 0;

  // state accumulator S'[k][v]: sacc[nt] lane(q4,m) reg r = S'[nt*16+q4*4+r][m]
  f32x4 sacc[4];
  #pragma unroll
  for (int i = 0; i < 4; i++) sacc[i] = zero4();

  auto loadF = [&](Frag& f, int n){
    const short* cp = bB + (size_t)n * CS2;
    f.wa0 = ld8(&cp[WAb + m*64 + q4*8]);
    f.wa1 = ld8(&cp[WAb + m*64 + 32 + q4*8]);
    f.wq0 = ld8(&cp[WQb + m*64 + q4*8]);
    f.wq1 = ld8(&cp[WQb + m*64 + 32 + q4*8]);
    f.qq  = ld8(&cp[QQb + m*32 + q4*8]);
    f.ak  = ld8(&cp[AKb + m*16 + (q4 & 1)*8]);
    f.li  = ld8(&cp[LIb + m*16 + (q4 & 1)*8]);
    f.kb0 = ld8(&cp[KBb +        l*8]);
    f.kb1 = ld8(&cp[KBb +  512 + l*8]);
    f.kb2 = ld8(&cp[KBb + 1024 + l*8]);
    f.kb3 = ld8(&cp[KBb + 1536 + l*8]);
    const float* fp = (const float*)(cp + FWb);
    f.fw0 = *(const f32x4*)(fp +      q4*4);
    f.fw1 = *(const f32x4*)(fp + 16 + q4*4);
    f.fw2 = *(const f32x4*)(fp + 32 + q4*4);
    f.fw3 = *(const f32x4*)(fp + 48 + q4*4);
    const float* vp = vBp + (size_t)n * 16 * HCc;
    #pragma unroll
    for (int j = 0; j < 8; j++) f.vv[j] = vp[((q4 & 1)*8 + j) * HCc];
  };

  auto body = [&](const Frag& f, int n){
    // state B-frags: B[k=q4*8+j(+32)][col=v=m] = S[v=m][k]
    short8 st0 = ld8(&s_st[wid][m*SW + q4*8]);
    short8 st1 = ld8(&s_st[wid][m*SW + 32 + q4*8]);
    short8 vBf;
    #pragma unroll
    for (int j = 0; j < 8; j++) vBf[j] = (q4 < 2) ? f2bs(f.vv[j]) : (short)0;
    short8 akA = (q4 < 2) ? f.ak : zero8();
    short8 liA = (q4 < 2) ? f.li : zero8();
    f32x4 abu = MFMA(akA, vBf, zero4());       // ak @ v
    abu = MFMA(f.wa0, st0, abu);               // + wa @ S^T
    abu = MFMA(f.wa1, st1, abu);
    f32x4 uu = MFMA(liA, shufK16(abu, q4, m), zero4());  // u = Linv @ ab_u
    short8 vu;                                  // B-frag [v ; u]
    #pragma unroll
    for (int j = 0; j < 8; j++){
      int row = (q4 - 2)*8 + j;
      int src = (((row >> 2) << 4) + m) & 63;
      float uv = __shfl(uu[j & 3], src, 64);
      vu[j] = (q4 < 2) ? vBf[j] : f2bs(uv);
    }
    f32x4 yy = MFMA(f.qq, vu, zero4());        // qk@v + qb@u
    yy = MFMA(f.wq0, st0, yy);                 // + wq @ S^T
    yy = MFMA(f.wq1, st1, yy);
    float* yp = yB + (size_t)(n * 16) * HCc;
    #pragma unroll
    for (int r = 0; r < 4; r++) yp[(q4*4 + r) * HCc] = yy[r];
    // state: S'[k][v] = fw[k]*S'[k][v] + kwfw^T@V + bwfw^T@U  (one MFMA per nt)
    f32x4 s;
    s = sacc[0] * f.fw0;  sacc[0] = MFMA(f.kb0, vu, s);
    s = sacc[1] * f.fw1;  sacc[1] = MFMA(f.kb1, vu, s);
    s = sacc[2] * f.fw2;  sacc[2] = MFMA(f.kb2, vu, s);
    s = sacc[3] * f.fw3;  sacc[3] = MFMA(f.kb3, vu, s);
    // shadow write: S[v=m][k=nt*16+q4*4+r] -> 4 consecutive shorts (b64 each)
    #pragma unroll
    for (int nt = 0; nt < 4; nt++){
      short4v p = { f2bs(sacc[nt][0]), f2bs(sacc[nt][1]),
                    f2bs(sacc[nt][2]), f2bs(sacc[nt][3]) };
      *(short4v*)&s_st[wid][m*SW + nt*16 + q4*4] = p;
    }
  };

  Frag fa, fb;
  loadF(fa, 0);
  loadF(fb, 1);
  for (int n = 0; n < NTc; n += 2){
    body(fa, n);
    if (n + 2 < NTc) loadF(fa, n + 2);
    body(fb, n + 1);
    if (n + 3 < NTc) loadF(fb, n + 3);
  }
}

// ================= fallback: single fused kernel (round-1, passing) ==========
struct Regs { float wv[16]; float xv[16]; float vv[8]; };

__global__ __launch_bounds__(256, 1)
void rwkv7_kernel(const float* __restrict__ w, const float* __restrict__ q,
                  const float* __restrict__ k, const float* __restrict__ v,
                  const float* __restrict__ a, const float* __restrict__ b,
                  float* __restrict__ out)
{
  __shared__ __align__(16) short s_wq[2][16*SW];
  __shared__ __align__(16) short s_wa[2][16*SW];
  __shared__ __align__(16) short s_kwi[2][16*SW];
  __shared__ __align__(16) short s_bwi[2][16*SW];
  __shared__ __align__(16) short s_kwT[2][64*ST];
  __shared__ __align__(16) short s_bwT[2][64*ST];
  __shared__ __align__(16) short s_ak[2][16*ST];
  __shared__ __align__(16) short s_qq[2][16*SQc];
  __shared__ __align__(16) short s_li[2][16*ST];
  __shared__ __align__(16) short s_n1[16*ST];
  __shared__ __align__(16) short s_n2[16*ST];
  __shared__ __align__(16) short s_n4[16*ST];
  __shared__ __align__(16) short s_st[4][16*SW];

  const int tid = threadIdx.x;
  const int wid = tid >> 6;
  const int l   = tid & 63;
  const int q4  = l >> 4;
  const int m   = l & 15;

  const int bh = blockIdx.x;
  const size_t hb = (size_t)(bh >> 5) * Tc * HCc + (size_t)(bh & 31) * Cc;

  const float* xsrc = (wid == 0) ? q : (wid == 1) ? a : (wid == 2) ? k : b;
  const float* wB = w + hb + l;
  const float* xB = xsrc + hb + l;
  const float* vBp = v + hb + wid * 16 + m;
  float* yB = out + hb + wid * 16 + m;

  f32x4 sacc[4];
  #pragma unroll
  for (int i = 0; i < 4; i++) sacc[i] = zero4();
  for (int i = tid; i < 4 * 16 * SW; i += 256) (&s_st[0][0])[i] = 0;
  __syncthreads();

  auto loadc = [&](Regs& r, int n){
    const float* wp = wB + (size_t)n * 16 * HCc;
    const float* xp = xB + (size_t)n * 16 * HCc;
    const float* vp = vBp + (size_t)n * 16 * HCc;
    #pragma unroll
    for (int t = 0; t < 16; t++) r.wv[t] = wp[t * HCc];
    #pragma unroll
    for (int t = 0; t < 16; t++) r.xv[t] = xp[t * HCc];
    #pragma unroll
    for (int j = 0; j < 8; j++){
      int row = (q4 & 1) * 8 + j;
      float val = vp[row * HCc];
      r.vv[j] = (q4 < 2) ? val : 0.f;
    }
  };

  auto body = [&](const Regs& rg, int n){
    const int bi = n & 1;
    float run = 1.f;
    float kv[16];
    #pragma unroll
    for (int t = 0; t < 16; t++){
      float dec = __expf(-__expf(rg.wv[t]));
      float ni = run;
      run *= dec;
      float x = rg.xv[t];
      if (wid == 0)      s_wq[bi][t * SW + l] = f2bs(x * run);
      else if (wid == 1) s_wa[bi][t * SW + l] = f2bs(x * ni);
      else {
        float kk = x * __builtin_amdgcn_rcpf(run);
        kv[t] = kk;
        short* dst = (wid == 2) ? s_kwi[bi] : s_bwi[bi];
        dst[t * SW + l] = f2bs(kk);
      }
    }
    const float fwv = run;
    if (wid >= 2){
      short* dst = (wid == 2) ? s_kwT[bi] : s_bwT[bi];
      #pragma unroll
      for (int i = 0; i < 4; i++){
        short4v pk = { f2bs(kv[4*i]*fwv), f2bs(kv[4*i+1]*fwv),
                       f2bs(kv[4*i+2]*fwv), f2bs(kv[4*i+3]*fwv) };
        *(short4v*)&dst[l * ST + 4 * i] = pk;
      }
    }
    __syncthreads();
    {
      const short* Aarr = (wid < 2) ? s_wa[bi] : s_wq[bi];
      const short* Barr = (wid == 0 || wid == 3) ? s_bwi[bi] : s_kwi[bi];
      short8 A0 = ld8(&Aarr[m * SW + q4 * 8]);
      short8 A1 = ld8(&Aarr[m * SW + q4 * 8 + 32]);
      short8 B0 = ld8(&Barr[m * SW + q4 * 8]);
      short8 B1 = ld8(&Barr[m * SW + q4 * 8 + 32]);
      f32x4 mm = MFMA(A0, B0, zero4());
      mm = MFMA(A1, B1, mm);
      #pragma unroll
      for (int r = 0; r < 4; r++){
        int t = q4 * 4 + r;
        bool keep = (wid < 2) ? (m < t) : (m <= t);
        mm[r] = keep ? mm[r] : 0.f;
      }
      if (wid == 1){
        #pragma unroll
        for (int r = 0; r < 4; r++) s_ak[bi][(q4*4+r)*ST + m] = f2bs(mm[r]);
      } else if (wid == 2){
        #pragma unroll
        for (int r = 0; r < 4; r++) s_qq[bi][(q4*4+r)*SQc + m] = f2bs(mm[r]);
      } else if (wid == 3){
        #pragma unroll
        for (int r = 0; r < 4; r++) s_qq[bi][(q4*4+r)*SQc + 16 + m] = f2bs(mm[r]);
      } else {
        #pragma unroll
        for (int r = 0; r < 4; r++) s_n1[(q4*4+r)*ST + m] = f2bs(mm[r]);
        short8 a1 = (q4 < 2) ? ld8(&s_n1[m*ST + q4*8]) : zero8();
        f32x4 p2 = MFMA(a1, shufK16(mm, q4, m), zero4());
        #pragma unroll
        for (int r = 0; r < 4; r++) s_n2[(q4*4+r)*ST + m] = f2bs(p2[r]);
        short8 a2 = (q4 < 2) ? ld8(&s_n2[m*ST + q4*8]) : zero8();
        f32x4 p4 = MFMA(a2, shufK16(p2, q4, m), zero4());
        #pragma unroll
        for (int r = 0; r < 4; r++) s_n4[(q4*4+r)*ST + m] = f2bs(p4[r]);
        short8 a4 = (q4 < 2) ? ld8(&s_n4[m*ST + q4*8]) : zero8();
        f32x4 R = MFMA(a4, shufK16(p4, q4, m), zero4());
        #pragma unroll
        for (int r = 0; r < 4; r++) R[r] += ((q4*4+r) == m) ? 1.f : 0.f;
        R = MFMA(a4, shufK16(R, q4, m), R);
        R = MFMA(a2, shufK16(R, q4, m), R);
        R = MFMA(a1, shufK16(R, q4, m), R);
        #pragma unroll
        for (int r = 0; r < 4; r++) s_li[bi][(q4*4+r)*ST + m] = f2bs(R[r]);
      }
    }
    __syncthreads();
    {
      short8 vBf;
      #pragma unroll
      for (int j = 0; j < 8; j++) vBf[j] = (q4 < 2) ? f2bs(rg.vv[j]) : (short)0;
      short8 akA  = (q4 < 2) ? ld8(&s_ak[bi][m*ST + q4*8]) : zero8();
      short8 waA0 = ld8(&s_wa[bi][m*SW + q4*8]);
      short8 waA1 = ld8(&s_wa[bi][m*SW + q4*8 + 32]);
      short8 st0  = ld8(&s_st[wid][m*SW + q4*8]);
      short8 st1  = ld8(&s_st[wid][m*SW + q4*8 + 32]);
      f32x4 abu = MFMA(akA, vBf, zero4());
      abu = MFMA(waA0, st0, abu);
      abu = MFMA(waA1, st1, abu);
      short8 LA = (q4 < 2) ? ld8(&s_li[bi][m*ST + q4*8]) : zero8();
      f32x4 uu = MFMA(LA, shufK16(abu, q4, m), zero4());
      short8 vu;
      #pragma unroll
      for (int j = 0; j < 8; j++){
        int row = (q4 - 2) * 8 + j;
        int src = (((row >> 2) << 4) + m) & 63;
        float uv = __shfl(uu[j & 3], src, 64);
        vu[j] = (q4 < 2) ? vBf[j] : f2bs(uv);
      }
      short8 qqA  = ld8(&s_qq[bi][m*SQc + q4*8]);
      short8 wqA0 = ld8(&s_wq[bi][m*SW + q4*8]);
      short8 wqA1 = ld8(&s_wq[bi][m*SW + q4*8 + 32]);
      f32x4 yy = MFMA(qqA, vu, zero4());
      yy = MFMA(wqA0, st0, yy);
      yy = MFMA(wqA1, st1, yy);
      float* yp = yB + (size_t)(n * 16) * HCc;
      #pragma unroll
      for (int r = 0; r < 4; r++) yp[(q4*4 + r) * HCc] = yy[r];
      #pragma unroll
      for (int nt = 0; nt < 4; nt++){
        float fwk = __shfl(fwv, nt * 16 + m, 64);
        f32x4 s = sacc[nt];
        #pragma unroll
        for (int r = 0; r < 4; r++) s[r] *= fwk;
        const short* kb = (q4 < 2) ? &s_kwT[bi][(nt*16+m)*ST + q4*8]
                                   : &s_bwT[bi][(nt*16+m)*ST + (q4-2)*8];
        s = MFMA(vu, ld8(kb), s);
        sacc[nt] = s;
        #pragma unroll
        for (int r = 0; r < 4; r++)
          s_st[wid][(q4*4+r)*SW + nt*16 + m] = f2bs(s[r]);
      }
    }
  };

  Regs ra, rb;
  loadc(ra, 0);
  for (int n = 0; n < NTc; n += 2){
    loadc(rb, n + 1);
    body(ra, n);
    if (n + 2 < NTc) loadc(ra, n + 2);
    body(rb, n + 1);
  }
}

extern "C" void kernel_launch(void* const* d_in, const int* in_sizes, int n_in,
                              void* d_out, int out_size, void* d_ws, size_t ws_size,
                              hipStream_t stream)
{
  (void)in_sizes; (void)n_in; (void)out_size;
  const float* w = (const float*)d_in[0];
  const float* q = (const float*)d_in[1];
  const float* k = (const float*)d_in[2];
  const float* v = (const float*)d_in[3];
  const float* a = (const float*)d_in[4];
  const float* b = (const float*)d_in[5];
  float* out = (float*)d_out;

  const size_t need = (size_t)Bc * Hc * NTc * CS2 * sizeof(short); // ~172 MB
  if (ws_size >= need){
    rwkv7_prep<<<dim3(Bc * Hc * NTc), dim3(256), 0, stream>>>(w, q, k, a, b, (short*)d_ws);
    rwkv7_scan<<<dim3(Bc * Hc), dim3(256), 0, stream>>>((const short*)d_ws, v, out);
  } else {
    rwkv7_kernel<<<dim3(Bc * Hc), dim3(256), 0, stream>>>(w, q, k, v, a, b, out);
  }
}